// Round 8
// baseline (231.995 us; speedup 1.0000x reference)
//
#include <hip/hip_runtime.h>
#include <hip/hip_bf16.h>

typedef __bf16 bf16x8 __attribute__((ext_vector_type(8)));
typedef float f32x4 __attribute__((ext_vector_type(4)));

#define NHEADS 12
#define TT 40
#define ST 1024
#define NTOK 1064
#define CDIM 768
#define HD 64
#define QSCALE 0.18033688f   // 0.125 * log2(e), folded into Q at QKV time

union U4 {
    uint4 u;
    __hip_bfloat16 h[8];
    bf16x8 v;
};

__device__ __forceinline__ void load_lds16(const __hip_bfloat16* g, __hip_bfloat16* s)
{
    __builtin_amdgcn_global_load_lds(
        (const __attribute__((address_space(1))) void*)g,
        (__attribute__((address_space(3))) void*)s, 16, 0, 0);
}

// Fused fp32 -> bf16 convert for x, qkv_w, proj_w (8 elems/thread).
__global__ __launch_bounds__(256) void f2b3(
    const float* __restrict__ x,  __hip_bfloat16* __restrict__ xo,
    const float* __restrict__ w,  __hip_bfloat16* __restrict__ wo,
    const float* __restrict__ p,  __hip_bfloat16* __restrict__ po)
{
    const float* in; __hip_bfloat16* out; int i;
    if (blockIdx.x < 3192)      { in = x; out = xo; i = blockIdx.x * 256 + threadIdx.x; if (i >= 817152) return; }
    else if (blockIdx.x < 4056) { in = w; out = wo; i = (blockIdx.x - 3192) * 256 + threadIdx.x; if (i >= 221184) return; }
    else                        { in = p; out = po; i = (blockIdx.x - 4056) * 256 + threadIdx.x; if (i >= 73728) return; }
    float4 a = ((const float4*)in)[2 * i];
    float4 b = ((const float4*)in)[2 * i + 1];
    U4 r;
    r.h[0] = __float2bfloat16(a.x); r.h[1] = __float2bfloat16(a.y);
    r.h[2] = __float2bfloat16(a.z); r.h[3] = __float2bfloat16(a.w);
    r.h[4] = __float2bfloat16(b.x); r.h[5] = __float2bfloat16(b.y);
    r.h[6] = __float2bfloat16(b.z); r.h[7] = __float2bfloat16(b.w);
    ((uint4*)out)[i] = r.u;
}

// ---------------------------------------------------------------------------
// 128x128x32 NT GEMM v10: DEPTH-2 async staging pipeline. 3 LDS buffers,
// raw s_barrier + counted s_waitcnt vmcnt(4) (never 0 in steady state).
// MODE 0: QKV scatter (Q pre-scaled; VT via LDS-transposed epilogue).
// MODE 3: proj+bias -> fp32. XCD-chunked bijective block swizzle.
// (verified win: QKV 73.5 -> <66 us in R6)
// ---------------------------------------------------------------------------
template <int MODE>
__global__ __launch_bounds__(256) void gemm128(
    const __hip_bfloat16* __restrict__ A, int lda, int M,
    const __hip_bfloat16* __restrict__ B, int ldb,
    int K,
    __hip_bfloat16* __restrict__ out0,
    __hip_bfloat16* __restrict__ out1,
    __hip_bfloat16* __restrict__ out2,
    float* __restrict__ outf,
    const float* __restrict__ biasf)
{
    __shared__ __hip_bfloat16 lds[24576];   // 48 KB: buf b at b*8192: A 4096 | B 4096

    const int tid = threadIdx.x;

    // bijective XCD chunked swizzle (ERRATA #11-safe for any block count)
    const int nbx = gridDim.x, nwg = nbx * gridDim.y;
    const int linear = blockIdx.y * nbx + blockIdx.x;
    const int qc = nwg >> 3, rc = nwg & 7;
    const int xcd = linear & 7, idx = linear >> 3;
    const int swz = (xcd < rc ? xcd * (qc + 1) : rc * (qc + 1) + (xcd - rc) * qc) + idx;
    const int bx = swz % nbx, by = swz / nbx;

    const int m0 = by * 128;
    const int n0 = bx * 128;
    const int w = tid >> 6, l = tid & 63, l15 = l & 15, lq = l >> 4;
    const int wm = w >> 1, wn = w & 1;

    const __hip_bfloat16* srcA[2];
    const __hip_bfloat16* srcB[2];
    int c8[2];
#pragma unroll
    for (int rd = 0; rd < 2; ++rd) {
        const int c = tid + rd * 256;
        const int r = c >> 2, cs = c & 3;
        const int gs = (cs - (r >> 1)) & 3;
        int ra = m0 + r; if (ra > M - 1) ra = M - 1;
        srcA[rd] = A + (long long)ra * lda + gs * 8;
        srcB[rd] = B + (long long)(n0 + r) * ldb + gs * 8;
        c8[rd] = c * 8;
    }

    int offA[4], offB[4];
#pragma unroll
    for (int t = 0; t < 4; ++t) {
        { const int r = wm * 64 + t * 16 + l15;
          offA[t] = r * 32 + ((lq + (r >> 1)) & 3) * 8; }
        { const int r = wn * 64 + t * 16 + l15;
          offB[t] = r * 32 + ((lq + (r >> 1)) & 3) * 8; }
    }

    f32x4 acc[4][4] = {};

    const int ksteps = K / 32;   // 24 for both dispatches (>= 2)
    // prologue: stage tile 0 -> buf 0, tile 1 -> buf 1
#pragma unroll
    for (int rd = 0; rd < 2; ++rd) {
        load_lds16(srcA[rd], lds + c8[rd]);
        load_lds16(srcB[rd], lds + 4096 + c8[rd]);
    }
#pragma unroll
    for (int rd = 0; rd < 2; ++rd) {
        load_lds16(srcA[rd] + 32, lds + 8192 + c8[rd]);
        load_lds16(srcB[rd] + 32, lds + 8192 + 4096 + c8[rd]);
    }

    int bcur = 0;
    for (int ks = 0; ks < ksteps; ++ks) {
        // wait for tile ks only (tile ks+1 stays in flight), then barrier
        if (ks + 1 < ksteps) { asm volatile("s_waitcnt vmcnt(4)" ::: "memory"); }
        else                 { asm volatile("s_waitcnt vmcnt(0)" ::: "memory"); }
        __builtin_amdgcn_s_barrier();
        __builtin_amdgcn_sched_barrier(0);   // pin: no ds_read hoisted above

        if (ks + 2 < ksteps) {   // stage tile ks+2 into the freed buffer
            const int bnxt = (bcur + 2 >= 3) ? bcur - 1 : bcur + 2;
            const int o = bnxt * 8192;
            const int koff = (ks + 2) * 32;
#pragma unroll
            for (int rd = 0; rd < 2; ++rd) {
                load_lds16(srcA[rd] + koff, lds + o + c8[rd]);
                load_lds16(srcB[rd] + koff, lds + o + 4096 + c8[rd]);
            }
        }

        const __hip_bfloat16* bufA = lds + bcur * 8192;
        const __hip_bfloat16* bufB = bufA + 4096;

        bf16x8 af[4], bfr[4];
#pragma unroll
        for (int t = 0; t < 4; ++t) af[t] = *(const bf16x8*)(bufA + offA[t]);
#pragma unroll
        for (int t = 0; t < 4; ++t) bfr[t] = *(const bf16x8*)(bufB + offB[t]);
#pragma unroll
        for (int tr = 0; tr < 4; ++tr)
#pragma unroll
            for (int tc = 0; tc < 4; ++tc)
                acc[tr][tc] = __builtin_amdgcn_mfma_f32_16x16x32_bf16(af[tr], bfr[tc], acc[tr][tc], 0, 0, 0);

        bcur = (bcur == 2) ? 0 : bcur + 1;
    }

    if (MODE == 0 && n0 >= 1536) {
        __hip_bfloat16* ldsT = lds;                  // [64 cols][136 rows]
#pragma unroll
        for (int hf = 0; hf < 2; ++hf) {
            __syncthreads();
            if (wn == hf) {
#pragma unroll
                for (int tr = 0; tr < 4; ++tr)
#pragma unroll
                    for (int tc = 0; tc < 4; ++tc) {
                        const int cl = tc * 16 + l15;
                        const int r = wm * 64 + tr * 16 + lq * 4;
                        U4 pk4;
                        pk4.h[0] = __float2bfloat16(acc[tr][tc][0]);
                        pk4.h[1] = __float2bfloat16(acc[tr][tc][1]);
                        pk4.h[2] = __float2bfloat16(acc[tr][tc][2]);
                        pk4.h[3] = __float2bfloat16(acc[tr][tc][3]);
                        *(uint2*)(ldsT + cl * 136 + r) = make_uint2(pk4.u.x, pk4.u.y);
                    }
            }
            __syncthreads();
            const int e = tid >> 2, rseg = (tid & 3) * 32;
            const int hh = (n0 + hf * 64 - 1536) >> 6;
#pragma unroll
            for (int j4 = 0; j4 < 4; ++j4) {
                const int r = rseg + j4 * 8;
                const int row = m0 + r;
                if (row >= 8 * NTOK) continue;
                const int b = row / NTOK;
                const int n = row - b * NTOK;
                __hip_bfloat16* dst = out2 + (((long long)(b * NHEADS + hh)) * HD + e) * NTOK + n;
                if (n + 8 <= NTOK) {
                    *(uint4*)dst = *(const uint4*)(ldsT + e * 136 + r);
                } else {
                    for (int j = 0; j < 8; ++j) {
                        const int row2 = row + j;
                        const int b2 = row2 / NTOK;
                        const int n2 = row2 - b2 * NTOK;
                        out2[(((long long)(b2 * NHEADS + hh)) * HD + e) * NTOK + n2] = ldsT[e * 136 + r + j];
                    }
                }
            }
        }
    } else {
#pragma unroll
        for (int tr = 0; tr < 4; ++tr) {
#pragma unroll
            for (int tc = 0; tc < 4; ++tc) {
                const int col = n0 + wn * 64 + tc * 16 + l15;
#pragma unroll
                for (int i = 0; i < 4; ++i) {
                    const int row = m0 + wm * 64 + tr * 16 + lq * 4 + i;
                    if (row >= M) continue;
                    const float v = acc[tr][tc][i];
                    if (MODE == 0) {
                        const int b = row / NTOK;
                        const int n = row - b * NTOK;
                        const int tq = col / CDIM;
                        const int rem = col - tq * CDIM;
                        const int h = rem >> 6;
                        const int e = rem & 63;
                        const long long gh = (long long)b * NHEADS + h;
                        if (tq == 0) out0[(gh * NTOK + n) * HD + e] = __float2bfloat16(v * QSCALE);  // Q
                        else         out1[(gh * NTOK + n) * HD + e] = __float2bfloat16(v);           // K
                    } else {
                        outf[(long long)row * CDIM + col] = v + biasf[col];
                    }
                }
            }
        }
    }
}

// ---------------------------------------------------------------------------
// Flash image attention v12 (512 thr = 8 waves) + fused text attention:
// grid (96, 5); qt < 4 -> image 256-row Q-tile (32 rows/wave as two 16-row
// halves rh), qt == 4 -> text path.
// v12 = v8 body (kf/vf fragment reads hoisted out of rh -> LDS read
// traffic per output HALVED; LDS pipe is the measured bottleneck) +
// __launch_bounds__(512, 2): VGPR budget 256 so the ~120-reg live set
// fits WITHOUT the scratch spills that killed v8 (VGPR was pinned at 64,
// WRITE_SIZE 21216 vs 12768 ideal). 480 blocks < 512 capacity at
// 2 blocks/CU -> still one dispatch wave.
// ---------------------------------------------------------------------------
__global__ __launch_bounds__(512, 2) void flash_img(
    const __hip_bfloat16* __restrict__ Q,   // [96][1064][64] (pre-scaled)
    const __hip_bfloat16* __restrict__ Kt,  // [96][1064][64]
    const __hip_bfloat16* __restrict__ VT,  // [96][64][1064]
    __hip_bfloat16* __restrict__ AO)        // [8][1064][768]
{
    __shared__ __hip_bfloat16 smem[16384];   // 32 KB
    const int gh = blockIdx.x;
    const int qt = blockIdx.y;
    const int tid = threadIdx.x;
    const int w = tid >> 6, l = tid & 63, l15 = l & 15, lq = l >> 4;

    const __hip_bfloat16* Kg = Kt + (long long)gh * NTOK * HD;
    const __hip_bfloat16* Vg = VT + (long long)gh * HD * NTOK;

    if (qt == 4) {
        // ---------------- text attention path (40 q over 40 k) ----------------
        const int b = gh / NHEADS;
        const int h = gh - b * NHEADS;
        float* fs = (float*)smem;
        float* Qs = fs;                  // [40][65]
        float* Ks = fs + 40 * 65;
        float* Vs = fs + 2 * 40 * 65;    // total 31200 B < 32 KB
        const __hip_bfloat16* Qg = Q + (long long)gh * NTOK * HD;
        for (int idx = tid; idx < 40 * 64; idx += 512) {
            const int n = idx >> 6;
            const int e = idx & 63;
            Qs[n * 65 + e] = __bfloat162float(Qg[n * HD + e]);
            Ks[n * 65 + e] = __bfloat162float(Kg[n * HD + e]);
            Vs[n * 65 + e] = __bfloat162float(Vg[(long long)e * NTOK + n]);
        }
        __syncthreads();
        for (int i = w; i < TT; i += 8) {
            float s = -1e30f;
            if (l < TT) {
                float a = 0.0f;
                for (int e = 0; e < 64; ++e) a += Qs[i * 65 + e] * Ks[l * 65 + e];
                s = a;                   // Q pre-scaled: already base-2 units
            }
            float m = s;
            for (int off = 32; off > 0; off >>= 1) m = fmaxf(m, __shfl_xor(m, off));
            float pr = (l < TT) ? exp2f(s - m) : 0.0f;
            float ssum = pr;
            for (int off = 32; off > 0; off >>= 1) ssum += __shfl_xor(ssum, off);
            pr /= ssum;
            float o = 0.0f;
            for (int j = 0; j < TT; ++j) o += __shfl(pr, j) * Vs[j * 65 + l];
            AO[((long long)b * NTOK + i) * CDIM + h * HD + l] = __float2bfloat16(o);
        }
        return;
    }

    // ---------------- image flash path (256-row Q tile) ----------------
    const __hip_bfloat16* Qg = Q + ((long long)gh * NTOK + TT + qt * 256) * HD;

    const int r0 = tid >> 3;
    const int g0 = ((tid & 7) - r0) & 7;

    bf16x8 qf[2][2];
#pragma unroll
    for (int rh = 0; rh < 2; ++rh)
#pragma unroll
        for (int kk = 0; kk < 2; ++kk)
            qf[rh][kk] = *(const bf16x8*)(Qg + (w * 32 + rh * 16 + l15) * HD + kk * 32 + lq * 8);

    f32x4 ot[2][4] = {};
    float lsum[2] = {0.0f, 0.0f};

    load_lds16(Kg + (long long)r0 * HD + g0 * 8, smem + tid * 8);
    load_lds16(Vg + (long long)r0 * NTOK + g0 * 8, smem + 4096 + tid * 8);

    const int segA = ((lq + l15) & 7) * 8;
    const int segB = ((4 + lq + l15) & 7) * 8;
    const int L0 = ((l & 16) ? 32 : 0) + l15;
    const int L1 = L0 + 16;
    const bool hi = (l & 32) != 0;

    for (int kt = 0; kt < 17; ++kt) {
        __syncthreads();

        if (kt < 16) {
            const int np = (kt + 1) * 64;
            __hip_bfloat16* kb = smem + ((kt + 1) & 1) * 8192;
            int kr = np + r0; if (kr > NTOK - 1) kr = NTOK - 1;
            int vc = np + g0 * 8; if (vc > NTOK - 8) vc = NTOK - 8;
            load_lds16(Kg + (long long)kr * HD + g0 * 8, kb + tid * 8);
            load_lds16(Vg + (long long)r0 * NTOK + vc, kb + 4096 + tid * 8);
        }

        const __hip_bfloat16* kbuf = smem + (kt & 1) * 8192;
        const __hip_bfloat16* vbuf = kbuf + 4096;

        // ---- QK^T: one kf read feeds BOTH rh halves ----
        f32x4 st[2][4] = {};
#pragma unroll
        for (int kk = 0; kk < 2; ++kk) {
            const int seg = kk ? segB : segA;
            bf16x8 kf[4];
#pragma unroll
            for (int t = 0; t < 4; ++t)
                kf[t] = *(const bf16x8*)(kbuf + (t * 16 + l15) * 64 + seg);
#pragma unroll
            for (int t = 0; t < 4; ++t) {
                st[0][t] = __builtin_amdgcn_mfma_f32_16x16x32_bf16(kf[t], qf[0][kk], st[0][t], 0, 0, 0);
                st[1][t] = __builtin_amdgcn_mfma_f32_16x16x32_bf16(kf[t], qf[1][kk], st[1][t], 0, 0, 0);
            }
        }

        if (kt == 16) {
#pragma unroll
            for (int rh = 0; rh < 2; ++rh)
#pragma unroll
                for (int t = 0; t < 4; ++t) {
                    const int nb = 1024 + t * 16 + lq * 4;
#pragma unroll
                    for (int i = 0; i < 4; ++i)
                        if (nb + i >= NTOK) st[rh][t][i] = -1e30f;
                }
        }

        unsigned pk[2][4][2];
#pragma unroll
        for (int rh = 0; rh < 2; ++rh) {
            float rs = 0.0f;
#pragma unroll
            for (int t = 0; t < 4; ++t)
#pragma unroll
                for (int i = 0; i < 4; ++i) {
                    const float p = exp2f(st[rh][t][i]);
                    st[rh][t][i] = p;
                    rs += p;
                }
            lsum[rh] += rs;
#pragma unroll
            for (int t = 0; t < 4; ++t)
#pragma unroll
                for (int h = 0; h < 2; ++h) {
                    __hip_bfloat162 b2 = __float22bfloat162_rn(
                        make_float2(st[rh][t][2 * h], st[rh][t][2 * h + 1]));
                    pk[rh][t][h] = *(unsigned*)&b2;
                }
        }

        // ---- PV: one vf read feeds BOTH rh halves ----
#pragma unroll
        for (int kk = 0; kk < 2; ++kk) {
            const int seg = kk ? segB : segA;
            bf16x8 vf[4];
#pragma unroll
            for (int te = 0; te < 4; ++te)
                vf[te] = *(const bf16x8*)(vbuf + (te * 16 + l15) * 64 + seg);
#pragma unroll
            for (int rh = 0; rh < 2; ++rh) {
                const unsigned a0 = __shfl(pk[rh][2 * kk][0], L0), b0 = __shfl(pk[rh][2 * kk + 1][0], L0);
                const unsigned a1 = __shfl(pk[rh][2 * kk][1], L0), b1 = __shfl(pk[rh][2 * kk + 1][1], L0);
                const unsigned a2 = __shfl(pk[rh][2 * kk][0], L1), b2 = __shfl(pk[rh][2 * kk + 1][0], L1);
                const unsigned a3 = __shfl(pk[rh][2 * kk][1], L1), b3 = __shfl(pk[rh][2 * kk + 1][1], L1);
                union { unsigned u[4]; bf16x8 v; } pu;
                pu.u[0] = hi ? b0 : a0;
                pu.u[1] = hi ? b1 : a1;
                pu.u[2] = hi ? b2 : a2;
                pu.u[3] = hi ? b3 : a3;
#pragma unroll
                for (int te = 0; te < 4; ++te)
                    ot[rh][te] = __builtin_amdgcn_mfma_f32_16x16x32_bf16(vf[te], pu.v, ot[rh][te], 0, 0, 0);
            }
        }
    }

#pragma unroll
    for (int rh = 0; rh < 2; ++rh) {
        lsum[rh] += __shfl_xor(lsum[rh], 16);
        lsum[rh] += __shfl_xor(lsum[rh], 32);
    }
    const float inv0 = 1.0f / lsum[0];
    const float inv1 = 1.0f / lsum[1];

    __hip_bfloat16* obuf = smem;                 // [128][72] per pass
    const int b = gh / NHEADS, h = gh - b * NHEADS;
#pragma unroll
    for (int p = 0; p < 2; ++p) {
        __syncthreads();
        if ((w >> 2) == p) {
#pragma unroll
            for (int rh = 0; rh < 2; ++rh) {
                const float inv = rh ? inv1 : inv0;
#pragma unroll
                for (int te = 0; te < 4; ++te) {
                    __hip_bfloat162 x0, x1;
                    x0.x = __float2bfloat16(ot[rh][te][0] * inv);
                    x0.y = __float2bfloat16(ot[rh][te][1] * inv);
                    x1.x = __float2bfloat16(ot[rh][te][2] * inv);
                    x1.y = __float2bfloat16(ot[rh][te][3] * inv);
                    uint2 u;
                    u.x = *(unsigned*)&x0;
                    u.y = *(unsigned*)&x1;
                    *(uint2*)(obuf + ((w & 3) * 32 + rh * 16 + l15) * 72 + te * 16 + lq * 4) = u;
                }
            }
        }
        __syncthreads();
        {
            const int r = tid >> 2, cc = (tid & 3) * 16;
            const int token = TT + qt * 256 + p * 128 + r;
            __hip_bfloat16* dst = AO + ((long long)b * NTOK + token) * CDIM + h * HD + cc;
            *(uint4*)dst       = *(const uint4*)(obuf + r * 72 + cc);
            *(uint4*)(dst + 8) = *(const uint4*)(obuf + r * 72 + cc + 8);
        }
    }
}

extern "C" void kernel_launch(void* const* d_in, const int* in_sizes, int n_in,
                              void* d_out, int out_size, void* d_ws, size_t ws_size,
                              hipStream_t stream)
{
    const float* x      = (const float*)d_in[0];
    const float* qkv_w  = (const float*)d_in[1];
    const float* proj_w = (const float*)d_in[2];
    const float* proj_b = (const float*)d_in[3];
    float* out = (float*)d_out;

    const long long QKV_ELEMS = (long long)8 * NHEADS * NTOK * HD;  // 6,537,216
    __hip_bfloat16* Q  = (__hip_bfloat16*)d_ws;
    __hip_bfloat16* Kt = Q + QKV_ELEMS;
    __hip_bfloat16* VT = Kt + QKV_ELEMS;
    __hip_bfloat16* AO = VT + QKV_ELEMS;        // [8][1064][768]; ALIASES xb (dead after QKV)
    __hip_bfloat16* xb = AO;
    __hip_bfloat16* wb = AO + QKV_ELEMS;        // qkv_w bf16 [2304][768]
    __hip_bfloat16* pb = wb + (long long)3 * CDIM * CDIM;  // proj_w bf16 [768][768]

    // 0. fused fp32 -> bf16 converts
    f2b3<<<4344, 256, 0, stream>>>(x, xb, qkv_w, wb, proj_w, pb);

    // 1. QKV GEMM: M=8512, N=2304, K=768 -> scatter Q (pre-scaled)/K/VT
    gemm128<0><<<dim3(18, 67), 256, 0, stream>>>(
        xb, CDIM, 8 * NTOK, wb, CDIM, CDIM,
        Q, Kt, VT, nullptr, nullptr);

    // 2+3. fused text + flash image attention (gh fastest -> XCD-local K/V)
    flash_img<<<dim3(96, 5), 512, 0, stream>>>(Q, Kt, VT, AO);

    // 4. proj GEMM + bias -> fp32 out
    gemm128<3><<<dim3(6, 67), 256, 0, stream>>>(
        AO, CDIM, 8 * NTOK, pb, CDIM, CDIM,
        nullptr, nullptr, nullptr, out, proj_b);
}

// Round 9
// 225.449 us; speedup vs baseline: 1.0290x; 1.0290x over previous
//
#include <hip/hip_runtime.h>
#include <hip/hip_bf16.h>

typedef __bf16 bf16x8 __attribute__((ext_vector_type(8)));
typedef float f32x4 __attribute__((ext_vector_type(4)));

#define NHEADS 12
#define TT 40
#define ST 1024
#define NTOK 1064
#define CDIM 768
#define HD 64
#define QSCALE 0.18033688f   // 0.125 * log2(e), folded into Q at QKV time

union U4 {
    uint4 u;
    __hip_bfloat16 h[8];
    bf16x8 v;
};

__device__ __forceinline__ void load_lds16(const __hip_bfloat16* g, __hip_bfloat16* s)
{
    __builtin_amdgcn_global_load_lds(
        (const __attribute__((address_space(1))) void*)g,
        (__attribute__((address_space(3))) void*)s, 16, 0, 0);
}

// Fused fp32 -> bf16 convert for x, qkv_w, proj_w (8 elems/thread).
__global__ __launch_bounds__(256) void f2b3(
    const float* __restrict__ x,  __hip_bfloat16* __restrict__ xo,
    const float* __restrict__ w,  __hip_bfloat16* __restrict__ wo,
    const float* __restrict__ p,  __hip_bfloat16* __restrict__ po)
{
    const float* in; __hip_bfloat16* out; int i;
    if (blockIdx.x < 3192)      { in = x; out = xo; i = blockIdx.x * 256 + threadIdx.x; if (i >= 817152) return; }
    else if (blockIdx.x < 4056) { in = w; out = wo; i = (blockIdx.x - 3192) * 256 + threadIdx.x; if (i >= 221184) return; }
    else                        { in = p; out = po; i = (blockIdx.x - 4056) * 256 + threadIdx.x; if (i >= 73728) return; }
    float4 a = ((const float4*)in)[2 * i];
    float4 b = ((const float4*)in)[2 * i + 1];
    U4 r;
    r.h[0] = __float2bfloat16(a.x); r.h[1] = __float2bfloat16(a.y);
    r.h[2] = __float2bfloat16(a.z); r.h[3] = __float2bfloat16(a.w);
    r.h[4] = __float2bfloat16(b.x); r.h[5] = __float2bfloat16(b.y);
    r.h[6] = __float2bfloat16(b.z); r.h[7] = __float2bfloat16(b.w);
    ((uint4*)out)[i] = r.u;
}

// ---------------------------------------------------------------------------
// 128x128x32 NT GEMM v10: DEPTH-2 async staging pipeline. 3 LDS buffers,
// raw s_barrier + counted s_waitcnt vmcnt(4) (never 0 in steady state).
// MODE 0: QKV scatter (Q pre-scaled; VT via LDS-transposed epilogue).
// MODE 3: proj+bias -> fp32. XCD-chunked bijective block swizzle.
// (verified win: QKV 73.5 -> <66 us in R6)
// ---------------------------------------------------------------------------
template <int MODE>
__global__ __launch_bounds__(256) void gemm128(
    const __hip_bfloat16* __restrict__ A, int lda, int M,
    const __hip_bfloat16* __restrict__ B, int ldb,
    int K,
    __hip_bfloat16* __restrict__ out0,
    __hip_bfloat16* __restrict__ out1,
    __hip_bfloat16* __restrict__ out2,
    float* __restrict__ outf,
    const float* __restrict__ biasf)
{
    __shared__ __hip_bfloat16 lds[24576];   // 48 KB: buf b at b*8192: A 4096 | B 4096

    const int tid = threadIdx.x;

    // bijective XCD chunked swizzle (ERRATA #11-safe for any block count)
    const int nbx = gridDim.x, nwg = nbx * gridDim.y;
    const int linear = blockIdx.y * nbx + blockIdx.x;
    const int qc = nwg >> 3, rc = nwg & 7;
    const int xcd = linear & 7, idx = linear >> 3;
    const int swz = (xcd < rc ? xcd * (qc + 1) : rc * (qc + 1) + (xcd - rc) * qc) + idx;
    const int bx = swz % nbx, by = swz / nbx;

    const int m0 = by * 128;
    const int n0 = bx * 128;
    const int w = tid >> 6, l = tid & 63, l15 = l & 15, lq = l >> 4;
    const int wm = w >> 1, wn = w & 1;

    const __hip_bfloat16* srcA[2];
    const __hip_bfloat16* srcB[2];
    int c8[2];
#pragma unroll
    for (int rd = 0; rd < 2; ++rd) {
        const int c = tid + rd * 256;
        const int r = c >> 2, cs = c & 3;
        const int gs = (cs - (r >> 1)) & 3;
        int ra = m0 + r; if (ra > M - 1) ra = M - 1;
        srcA[rd] = A + (long long)ra * lda + gs * 8;
        srcB[rd] = B + (long long)(n0 + r) * ldb + gs * 8;
        c8[rd] = c * 8;
    }

    int offA[4], offB[4];
#pragma unroll
    for (int t = 0; t < 4; ++t) {
        { const int r = wm * 64 + t * 16 + l15;
          offA[t] = r * 32 + ((lq + (r >> 1)) & 3) * 8; }
        { const int r = wn * 64 + t * 16 + l15;
          offB[t] = r * 32 + ((lq + (r >> 1)) & 3) * 8; }
    }

    f32x4 acc[4][4] = {};

    const int ksteps = K / 32;   // 24 for both dispatches (>= 2)
    // prologue: stage tile 0 -> buf 0, tile 1 -> buf 1
#pragma unroll
    for (int rd = 0; rd < 2; ++rd) {
        load_lds16(srcA[rd], lds + c8[rd]);
        load_lds16(srcB[rd], lds + 4096 + c8[rd]);
    }
#pragma unroll
    for (int rd = 0; rd < 2; ++rd) {
        load_lds16(srcA[rd] + 32, lds + 8192 + c8[rd]);
        load_lds16(srcB[rd] + 32, lds + 8192 + 4096 + c8[rd]);
    }

    int bcur = 0;
    for (int ks = 0; ks < ksteps; ++ks) {
        // wait for tile ks only (tile ks+1 stays in flight), then barrier
        if (ks + 1 < ksteps) { asm volatile("s_waitcnt vmcnt(4)" ::: "memory"); }
        else                 { asm volatile("s_waitcnt vmcnt(0)" ::: "memory"); }
        __builtin_amdgcn_s_barrier();
        __builtin_amdgcn_sched_barrier(0);   // pin: no ds_read hoisted above

        if (ks + 2 < ksteps) {   // stage tile ks+2 into the freed buffer
            const int bnxt = (bcur + 2 >= 3) ? bcur - 1 : bcur + 2;
            const int o = bnxt * 8192;
            const int koff = (ks + 2) * 32;
#pragma unroll
            for (int rd = 0; rd < 2; ++rd) {
                load_lds16(srcA[rd] + koff, lds + o + c8[rd]);
                load_lds16(srcB[rd] + koff, lds + o + 4096 + c8[rd]);
            }
        }

        const __hip_bfloat16* bufA = lds + bcur * 8192;
        const __hip_bfloat16* bufB = bufA + 4096;

        bf16x8 af[4], bfr[4];
#pragma unroll
        for (int t = 0; t < 4; ++t) af[t] = *(const bf16x8*)(bufA + offA[t]);
#pragma unroll
        for (int t = 0; t < 4; ++t) bfr[t] = *(const bf16x8*)(bufB + offB[t]);
#pragma unroll
        for (int tr = 0; tr < 4; ++tr)
#pragma unroll
            for (int tc = 0; tc < 4; ++tc)
                acc[tr][tc] = __builtin_amdgcn_mfma_f32_16x16x32_bf16(af[tr], bfr[tc], acc[tr][tc], 0, 0, 0);

        bcur = (bcur == 2) ? 0 : bcur + 1;
    }

    if (MODE == 0 && n0 >= 1536) {
        __hip_bfloat16* ldsT = lds;                  // [64 cols][136 rows]
#pragma unroll
        for (int hf = 0; hf < 2; ++hf) {
            __syncthreads();
            if (wn == hf) {
#pragma unroll
                for (int tr = 0; tr < 4; ++tr)
#pragma unroll
                    for (int tc = 0; tc < 4; ++tc) {
                        const int cl = tc * 16 + l15;
                        const int r = wm * 64 + tr * 16 + lq * 4;
                        U4 pk4;
                        pk4.h[0] = __float2bfloat16(acc[tr][tc][0]);
                        pk4.h[1] = __float2bfloat16(acc[tr][tc][1]);
                        pk4.h[2] = __float2bfloat16(acc[tr][tc][2]);
                        pk4.h[3] = __float2bfloat16(acc[tr][tc][3]);
                        *(uint2*)(ldsT + cl * 136 + r) = make_uint2(pk4.u.x, pk4.u.y);
                    }
            }
            __syncthreads();
            const int e = tid >> 2, rseg = (tid & 3) * 32;
            const int hh = (n0 + hf * 64 - 1536) >> 6;
#pragma unroll
            for (int j4 = 0; j4 < 4; ++j4) {
                const int r = rseg + j4 * 8;
                const int row = m0 + r;
                if (row >= 8 * NTOK) continue;
                const int b = row / NTOK;
                const int n = row - b * NTOK;
                __hip_bfloat16* dst = out2 + (((long long)(b * NHEADS + hh)) * HD + e) * NTOK + n;
                if (n + 8 <= NTOK) {
                    *(uint4*)dst = *(const uint4*)(ldsT + e * 136 + r);
                } else {
                    for (int j = 0; j < 8; ++j) {
                        const int row2 = row + j;
                        const int b2 = row2 / NTOK;
                        const int n2 = row2 - b2 * NTOK;
                        out2[(((long long)(b2 * NHEADS + hh)) * HD + e) * NTOK + n2] = ldsT[e * 136 + r + j];
                    }
                }
            }
        }
    } else {
#pragma unroll
        for (int tr = 0; tr < 4; ++tr) {
#pragma unroll
            for (int tc = 0; tc < 4; ++tc) {
                const int col = n0 + wn * 64 + tc * 16 + l15;
#pragma unroll
                for (int i = 0; i < 4; ++i) {
                    const int row = m0 + wm * 64 + tr * 16 + lq * 4 + i;
                    if (row >= M) continue;
                    const float v = acc[tr][tc][i];
                    if (MODE == 0) {
                        const int b = row / NTOK;
                        const int n = row - b * NTOK;
                        const int tq = col / CDIM;
                        const int rem = col - tq * CDIM;
                        const int h = rem >> 6;
                        const int e = rem & 63;
                        const long long gh = (long long)b * NHEADS + h;
                        if (tq == 0) out0[(gh * NTOK + n) * HD + e] = __float2bfloat16(v * QSCALE);  // Q
                        else         out1[(gh * NTOK + n) * HD + e] = __float2bfloat16(v);           // K
                    } else {
                        outf[(long long)row * CDIM + col] = v + biasf[col];
                    }
                }
            }
        }
    }
}

// ---------------------------------------------------------------------------
// Flash image attention v13 (256 thr = 4 waves) + fused text attention:
// grid (96, 9); qt < 8 -> image 128-row Q-tile (32 rows/wave as two 16-row
// halves rh), qt == 8 -> text path.
// v13 = v12's fragment-sharing body (one kf/vf LDS read feeds both rh
// halves -> per-output LDS read traffic halves; VGPR-proven 84 in R8, no
// spills) but in 4-WAVE blocks so the grid stays 864 (3.4 blocks/CU TLP,
// which R8 showed is what v12's 8-wave/480-block version lost).
// ---------------------------------------------------------------------------
__global__ __launch_bounds__(256, 4) void flash_img(
    const __hip_bfloat16* __restrict__ Q,   // [96][1064][64] (pre-scaled)
    const __hip_bfloat16* __restrict__ Kt,  // [96][1064][64]
    const __hip_bfloat16* __restrict__ VT,  // [96][64][1064]
    __hip_bfloat16* __restrict__ AO)        // [8][1064][768]
{
    __shared__ __hip_bfloat16 smem[16384];   // 32 KB: 2 bufs of 8192 (K 4096 | V 4096)
    const int gh = blockIdx.x;
    const int qt = blockIdx.y;
    const int tid = threadIdx.x;
    const int w = tid >> 6, l = tid & 63, l15 = l & 15, lq = l >> 4;

    const __hip_bfloat16* Kg = Kt + (long long)gh * NTOK * HD;
    const __hip_bfloat16* Vg = VT + (long long)gh * HD * NTOK;

    if (qt == 8) {
        // ---------------- text attention path (40 q over 40 k) ----------------
        const int b = gh / NHEADS;
        const int h = gh - b * NHEADS;
        float* fs = (float*)smem;
        float* Qs = fs;                  // [40][65]... total 31200 B < 32 KB
        float* Ks = fs + 40 * 65;
        float* Vs = fs + 2 * 40 * 65;
        const __hip_bfloat16* Qg = Q + (long long)gh * NTOK * HD;
        for (int idx = tid; idx < 40 * 64; idx += 256) {
            const int n = idx >> 6;
            const int e = idx & 63;
            Qs[n * 65 + e] = __bfloat162float(Qg[n * HD + e]);
            Ks[n * 65 + e] = __bfloat162float(Kg[n * HD + e]);
            Vs[n * 65 + e] = __bfloat162float(Vg[(long long)e * NTOK + n]);
        }
        __syncthreads();
        for (int i = w; i < TT; i += 4) {
            float s = -1e30f;
            if (l < TT) {
                float a = 0.0f;
                for (int e = 0; e < 64; ++e) a += Qs[i * 65 + e] * Ks[l * 65 + e];
                s = a;                   // Q pre-scaled: already base-2 units
            }
            float m = s;
            for (int off = 32; off > 0; off >>= 1) m = fmaxf(m, __shfl_xor(m, off));
            float pr = (l < TT) ? exp2f(s - m) : 0.0f;
            float ssum = pr;
            for (int off = 32; off > 0; off >>= 1) ssum += __shfl_xor(ssum, off);
            pr /= ssum;
            float o = 0.0f;
            for (int j = 0; j < TT; ++j) o += __shfl(pr, j) * Vs[j * 65 + l];
            AO[((long long)b * NTOK + i) * CDIM + h * HD + l] = __float2bfloat16(o);
        }
        return;
    }

    // ---------------- image flash path (128-row Q tile, 32 rows/wave) --------
    const __hip_bfloat16* Qg = Q + ((long long)gh * NTOK + TT + qt * 128) * HD;

    bf16x8 qf[2][2];
#pragma unroll
    for (int rh = 0; rh < 2; ++rh)
#pragma unroll
        for (int kk = 0; kk < 2; ++kk)
            qf[rh][kk] = *(const bf16x8*)(Qg + (w * 32 + rh * 16 + l15) * HD + kk * 32 + lq * 8);

    f32x4 ot[2][4] = {};
    float lsum[2] = {0.0f, 0.0f};

    // stage tile t2 into buffer kb (4 global_load_lds per thread, 256 thr)
    auto stage = [&](int t2, __hip_bfloat16* kb) {
        const int np = t2 * 64;
#pragma unroll
        for (int half = 0; half < 2; ++half) {
            const int c = tid + half * 256;
            const int r0 = c >> 3;
            const int g0 = ((c & 7) - r0) & 7;
            int kr = np + r0; if (kr > NTOK - 1) kr = NTOK - 1;
            int vc = np + g0 * 8; if (vc > NTOK - 8) vc = NTOK - 8;
            load_lds16(Kg + (long long)kr * HD + g0 * 8, kb + c * 8);
            load_lds16(Vg + (long long)r0 * NTOK + vc, kb + 4096 + c * 8);
        }
    };

    stage(0, smem);

    const int segA = ((lq + l15) & 7) * 8;
    const int segB = ((4 + lq + l15) & 7) * 8;
    const int L0 = ((l & 16) ? 32 : 0) + l15;
    const int L1 = L0 + 16;
    const bool hi = (l & 32) != 0;

    for (int kt = 0; kt < 17; ++kt) {
        __syncthreads();

        if (kt < 16) stage(kt + 1, smem + ((kt + 1) & 1) * 8192);

        const __hip_bfloat16* kbuf = smem + (kt & 1) * 8192;
        const __hip_bfloat16* vbuf = kbuf + 4096;

        // ---- QK^T: one kf read feeds BOTH rh halves ----
        f32x4 st[2][4] = {};
#pragma unroll
        for (int kk = 0; kk < 2; ++kk) {
            const int seg = kk ? segB : segA;
            bf16x8 kf[4];
#pragma unroll
            for (int t = 0; t < 4; ++t)
                kf[t] = *(const bf16x8*)(kbuf + (t * 16 + l15) * 64 + seg);
#pragma unroll
            for (int t = 0; t < 4; ++t) {
                st[0][t] = __builtin_amdgcn_mfma_f32_16x16x32_bf16(kf[t], qf[0][kk], st[0][t], 0, 0, 0);
                st[1][t] = __builtin_amdgcn_mfma_f32_16x16x32_bf16(kf[t], qf[1][kk], st[1][t], 0, 0, 0);
            }
        }

        if (kt == 16) {
#pragma unroll
            for (int rh = 0; rh < 2; ++rh)
#pragma unroll
                for (int t = 0; t < 4; ++t) {
                    const int nb = 1024 + t * 16 + lq * 4;
#pragma unroll
                    for (int i = 0; i < 4; ++i)
                        if (nb + i >= NTOK) st[rh][t][i] = -1e30f;
                }
        }

        unsigned pk[2][4][2];
#pragma unroll
        for (int rh = 0; rh < 2; ++rh) {
            float rs = 0.0f;
#pragma unroll
            for (int t = 0; t < 4; ++t)
#pragma unroll
                for (int i = 0; i < 4; ++i) {
                    const float p = exp2f(st[rh][t][i]);
                    st[rh][t][i] = p;
                    rs += p;
                }
            lsum[rh] += rs;
#pragma unroll
            for (int t = 0; t < 4; ++t)
#pragma unroll
                for (int h = 0; h < 2; ++h) {
                    __hip_bfloat162 b2 = __float22bfloat162_rn(
                        make_float2(st[rh][t][2 * h], st[rh][t][2 * h + 1]));
                    pk[rh][t][h] = *(unsigned*)&b2;
                }
        }

        // ---- PV: one vf read feeds BOTH rh halves ----
#pragma unroll
        for (int kk = 0; kk < 2; ++kk) {
            const int seg = kk ? segB : segA;
            bf16x8 vf[4];
#pragma unroll
            for (int te = 0; te < 4; ++te)
                vf[te] = *(const bf16x8*)(vbuf + (te * 16 + l15) * 64 + seg);
#pragma unroll
            for (int rh = 0; rh < 2; ++rh) {
                const unsigned a0 = __shfl(pk[rh][2 * kk][0], L0), b0 = __shfl(pk[rh][2 * kk + 1][0], L0);
                const unsigned a1 = __shfl(pk[rh][2 * kk][1], L0), b1 = __shfl(pk[rh][2 * kk + 1][1], L0);
                const unsigned a2 = __shfl(pk[rh][2 * kk][0], L1), b2 = __shfl(pk[rh][2 * kk + 1][0], L1);
                const unsigned a3 = __shfl(pk[rh][2 * kk][1], L1), b3 = __shfl(pk[rh][2 * kk + 1][1], L1);
                union { unsigned u[4]; bf16x8 v; } pu;
                pu.u[0] = hi ? b0 : a0;
                pu.u[1] = hi ? b1 : a1;
                pu.u[2] = hi ? b2 : a2;
                pu.u[3] = hi ? b3 : a3;
#pragma unroll
                for (int te = 0; te < 4; ++te)
                    ot[rh][te] = __builtin_amdgcn_mfma_f32_16x16x32_bf16(vf[te], pu.v, ot[rh][te], 0, 0, 0);
            }
        }
    }

#pragma unroll
    for (int rh = 0; rh < 2; ++rh) {
        lsum[rh] += __shfl_xor(lsum[rh], 16);
        lsum[rh] += __shfl_xor(lsum[rh], 32);
    }
    const float inv0 = 1.0f / lsum[0];
    const float inv1 = 1.0f / lsum[1];

    __syncthreads();
    __hip_bfloat16* obuf = smem;                 // [128][72] = 18 KB
#pragma unroll
    for (int rh = 0; rh < 2; ++rh) {
        const float inv = rh ? inv1 : inv0;
#pragma unroll
        for (int te = 0; te < 4; ++te) {
            __hip_bfloat162 x0, x1;
            x0.x = __float2bfloat16(ot[rh][te][0] * inv);
            x0.y = __float2bfloat16(ot[rh][te][1] * inv);
            x1.x = __float2bfloat16(ot[rh][te][2] * inv);
            x1.y = __float2bfloat16(ot[rh][te][3] * inv);
            uint2 u;
            u.x = *(unsigned*)&x0;
            u.y = *(unsigned*)&x1;
            *(uint2*)(obuf + (w * 32 + rh * 16 + l15) * 72 + te * 16 + lq * 4) = u;
        }
    }
    __syncthreads();
    {
        const int b = gh / NHEADS, h = gh - b * NHEADS;
        const int r = tid >> 1, cc = (tid & 1) * 32;
        const int token = TT + qt * 128 + r;
        __hip_bfloat16* dst = AO + ((long long)b * NTOK + token) * CDIM + h * HD + cc;
        *(uint4*)dst        = *(const uint4*)(obuf + r * 72 + cc);
        *(uint4*)(dst + 8)  = *(const uint4*)(obuf + r * 72 + cc + 8);
        *(uint4*)(dst + 16) = *(const uint4*)(obuf + r * 72 + cc + 16);
        *(uint4*)(dst + 24) = *(const uint4*)(obuf + r * 72 + cc + 24);
    }
}

extern "C" void kernel_launch(void* const* d_in, const int* in_sizes, int n_in,
                              void* d_out, int out_size, void* d_ws, size_t ws_size,
                              hipStream_t stream)
{
    const float* x      = (const float*)d_in[0];
    const float* qkv_w  = (const float*)d_in[1];
    const float* proj_w = (const float*)d_in[2];
    const float* proj_b = (const float*)d_in[3];
    float* out = (float*)d_out;

    const long long QKV_ELEMS = (long long)8 * NHEADS * NTOK * HD;  // 6,537,216
    __hip_bfloat16* Q  = (__hip_bfloat16*)d_ws;
    __hip_bfloat16* Kt = Q + QKV_ELEMS;
    __hip_bfloat16* VT = Kt + QKV_ELEMS;
    __hip_bfloat16* AO = VT + QKV_ELEMS;        // [8][1064][768]; ALIASES xb (dead after QKV)
    __hip_bfloat16* xb = AO;
    __hip_bfloat16* wb = AO + QKV_ELEMS;        // qkv_w bf16 [2304][768]
    __hip_bfloat16* pb = wb + (long long)3 * CDIM * CDIM;  // proj_w bf16 [768][768]

    // 0. fused fp32 -> bf16 converts
    f2b3<<<4344, 256, 0, stream>>>(x, xb, qkv_w, wb, proj_w, pb);

    // 1. QKV GEMM: M=8512, N=2304, K=768 -> scatter Q (pre-scaled)/K/VT
    gemm128<0><<<dim3(18, 67), 256, 0, stream>>>(
        xb, CDIM, 8 * NTOK, wb, CDIM, CDIM,
        Q, Kt, VT, nullptr, nullptr);

    // 2+3. fused text + flash image attention (gh fastest -> XCD-local K/V)
    flash_img<<<dim3(96, 9), 256, 0, stream>>>(Q, Kt, VT, AO);

    // 4. proj GEMM + bias -> fp32 out
    gemm128<3><<<dim3(6, 67), 256, 0, stream>>>(
        AO, CDIM, 8 * NTOK, pb, CDIM, CDIM,
        nullptr, nullptr, nullptr, out, proj_b);
}

// Round 10
// 220.330 us; speedup vs baseline: 1.0529x; 1.0232x over previous
//
#include <hip/hip_runtime.h>
#include <hip/hip_bf16.h>

typedef __bf16 bf16x8 __attribute__((ext_vector_type(8)));
typedef float f32x4 __attribute__((ext_vector_type(4)));

#define NHEADS 12
#define TT 40
#define ST 1024
#define NTOK 1064
#define CDIM 768
#define HD 64
#define QSCALE 0.18033688f   // 0.125 * log2(e), folded into Q at QKV time

union U4 {
    uint4 u;
    __hip_bfloat16 h[8];
    bf16x8 v;
};

__device__ __forceinline__ void load_lds16(const __hip_bfloat16* g, __hip_bfloat16* s)
{
    __builtin_amdgcn_global_load_lds(
        (const __attribute__((address_space(1))) void*)g,
        (__attribute__((address_space(3))) void*)s, 16, 0, 0);
}

// Fused fp32 -> bf16 convert for x, qkv_w, proj_w (8 elems/thread).
__global__ __launch_bounds__(256) void f2b3(
    const float* __restrict__ x,  __hip_bfloat16* __restrict__ xo,
    const float* __restrict__ w,  __hip_bfloat16* __restrict__ wo,
    const float* __restrict__ p,  __hip_bfloat16* __restrict__ po)
{
    const float* in; __hip_bfloat16* out; int i;
    if (blockIdx.x < 3192)      { in = x; out = xo; i = blockIdx.x * 256 + threadIdx.x; if (i >= 817152) return; }
    else if (blockIdx.x < 4056) { in = w; out = wo; i = (blockIdx.x - 3192) * 256 + threadIdx.x; if (i >= 221184) return; }
    else                        { in = p; out = po; i = (blockIdx.x - 4056) * 256 + threadIdx.x; if (i >= 73728) return; }
    float4 a = ((const float4*)in)[2 * i];
    float4 b = ((const float4*)in)[2 * i + 1];
    U4 r;
    r.h[0] = __float2bfloat16(a.x); r.h[1] = __float2bfloat16(a.y);
    r.h[2] = __float2bfloat16(a.z); r.h[3] = __float2bfloat16(a.w);
    r.h[4] = __float2bfloat16(b.x); r.h[5] = __float2bfloat16(b.y);
    r.h[6] = __float2bfloat16(b.z); r.h[7] = __float2bfloat16(b.w);
    ((uint4*)out)[i] = r.u;
}

// ---------------------------------------------------------------------------
// 128x128x32 NT GEMM v10: DEPTH-2 async staging pipeline. 3 LDS buffers,
// raw s_barrier + counted s_waitcnt vmcnt(4) (never 0 in steady state).
// MODE 0: QKV scatter (Q pre-scaled; VT via LDS-transposed epilogue).
// MODE 3: proj+bias -> fp32. XCD-chunked bijective block swizzle.
// (verified win: QKV 73.5 -> ~67 us in R6)
// ---------------------------------------------------------------------------
template <int MODE>
__global__ __launch_bounds__(256) void gemm128(
    const __hip_bfloat16* __restrict__ A, int lda, int M,
    const __hip_bfloat16* __restrict__ B, int ldb,
    int K,
    __hip_bfloat16* __restrict__ out0,
    __hip_bfloat16* __restrict__ out1,
    __hip_bfloat16* __restrict__ out2,
    float* __restrict__ outf,
    const float* __restrict__ biasf)
{
    __shared__ __hip_bfloat16 lds[24576];   // 48 KB: buf b at b*8192: A 4096 | B 4096

    const int tid = threadIdx.x;

    // bijective XCD chunked swizzle (ERRATA #11-safe for any block count)
    const int nbx = gridDim.x, nwg = nbx * gridDim.y;
    const int linear = blockIdx.y * nbx + blockIdx.x;
    const int qc = nwg >> 3, rc = nwg & 7;
    const int xcd = linear & 7, idx = linear >> 3;
    const int swz = (xcd < rc ? xcd * (qc + 1) : rc * (qc + 1) + (xcd - rc) * qc) + idx;
    const int bx = swz % nbx, by = swz / nbx;

    const int m0 = by * 128;
    const int n0 = bx * 128;
    const int w = tid >> 6, l = tid & 63, l15 = l & 15, lq = l >> 4;
    const int wm = w >> 1, wn = w & 1;

    const __hip_bfloat16* srcA[2];
    const __hip_bfloat16* srcB[2];
    int c8[2];
#pragma unroll
    for (int rd = 0; rd < 2; ++rd) {
        const int c = tid + rd * 256;
        const int r = c >> 2, cs = c & 3;
        const int gs = (cs - (r >> 1)) & 3;
        int ra = m0 + r; if (ra > M - 1) ra = M - 1;
        srcA[rd] = A + (long long)ra * lda + gs * 8;
        srcB[rd] = B + (long long)(n0 + r) * ldb + gs * 8;
        c8[rd] = c * 8;
    }

    int offA[4], offB[4];
#pragma unroll
    for (int t = 0; t < 4; ++t) {
        { const int r = wm * 64 + t * 16 + l15;
          offA[t] = r * 32 + ((lq + (r >> 1)) & 3) * 8; }
        { const int r = wn * 64 + t * 16 + l15;
          offB[t] = r * 32 + ((lq + (r >> 1)) & 3) * 8; }
    }

    f32x4 acc[4][4] = {};

    const int ksteps = K / 32;   // 24 for both dispatches (>= 2)
    // prologue: stage tile 0 -> buf 0, tile 1 -> buf 1
#pragma unroll
    for (int rd = 0; rd < 2; ++rd) {
        load_lds16(srcA[rd], lds + c8[rd]);
        load_lds16(srcB[rd], lds + 4096 + c8[rd]);
    }
#pragma unroll
    for (int rd = 0; rd < 2; ++rd) {
        load_lds16(srcA[rd] + 32, lds + 8192 + c8[rd]);
        load_lds16(srcB[rd] + 32, lds + 8192 + 4096 + c8[rd]);
    }

    int bcur = 0;
    for (int ks = 0; ks < ksteps; ++ks) {
        // wait for tile ks only (tile ks+1 stays in flight), then barrier
        if (ks + 1 < ksteps) { asm volatile("s_waitcnt vmcnt(4)" ::: "memory"); }
        else                 { asm volatile("s_waitcnt vmcnt(0)" ::: "memory"); }
        __builtin_amdgcn_s_barrier();
        __builtin_amdgcn_sched_barrier(0);   // pin: no ds_read hoisted above

        if (ks + 2 < ksteps) {   // stage tile ks+2 into the freed buffer
            const int bnxt = (bcur + 2 >= 3) ? bcur - 1 : bcur + 2;
            const int o = bnxt * 8192;
            const int koff = (ks + 2) * 32;
#pragma unroll
            for (int rd = 0; rd < 2; ++rd) {
                load_lds16(srcA[rd] + koff, lds + o + c8[rd]);
                load_lds16(srcB[rd] + koff, lds + o + 4096 + c8[rd]);
            }
        }

        const __hip_bfloat16* bufA = lds + bcur * 8192;
        const __hip_bfloat16* bufB = bufA + 4096;

        bf16x8 af[4], bfr[4];
#pragma unroll
        for (int t = 0; t < 4; ++t) af[t] = *(const bf16x8*)(bufA + offA[t]);
#pragma unroll
        for (int t = 0; t < 4; ++t) bfr[t] = *(const bf16x8*)(bufB + offB[t]);
#pragma unroll
        for (int tr = 0; tr < 4; ++tr)
#pragma unroll
            for (int tc = 0; tc < 4; ++tc)
                acc[tr][tc] = __builtin_amdgcn_mfma_f32_16x16x32_bf16(af[tr], bfr[tc], acc[tr][tc], 0, 0, 0);

        bcur = (bcur == 2) ? 0 : bcur + 1;
    }

    if (MODE == 0 && n0 >= 1536) {
        __hip_bfloat16* ldsT = lds;                  // [64 cols][136 rows]
#pragma unroll
        for (int hf = 0; hf < 2; ++hf) {
            __syncthreads();
            if (wn == hf) {
#pragma unroll
                for (int tr = 0; tr < 4; ++tr)
#pragma unroll
                    for (int tc = 0; tc < 4; ++tc) {
                        const int cl = tc * 16 + l15;
                        const int r = wm * 64 + tr * 16 + lq * 4;
                        U4 pk4;
                        pk4.h[0] = __float2bfloat16(acc[tr][tc][0]);
                        pk4.h[1] = __float2bfloat16(acc[tr][tc][1]);
                        pk4.h[2] = __float2bfloat16(acc[tr][tc][2]);
                        pk4.h[3] = __float2bfloat16(acc[tr][tc][3]);
                        *(uint2*)(ldsT + cl * 136 + r) = make_uint2(pk4.u.x, pk4.u.y);
                    }
            }
            __syncthreads();
            const int e = tid >> 2, rseg = (tid & 3) * 32;
            const int hh = (n0 + hf * 64 - 1536) >> 6;
#pragma unroll
            for (int j4 = 0; j4 < 4; ++j4) {
                const int r = rseg + j4 * 8;
                const int row = m0 + r;
                if (row >= 8 * NTOK) continue;
                const int b = row / NTOK;
                const int n = row - b * NTOK;
                __hip_bfloat16* dst = out2 + (((long long)(b * NHEADS + hh)) * HD + e) * NTOK + n;
                if (n + 8 <= NTOK) {
                    *(uint4*)dst = *(const uint4*)(ldsT + e * 136 + r);
                } else {
                    for (int j = 0; j < 8; ++j) {
                        const int row2 = row + j;
                        const int b2 = row2 / NTOK;
                        const int n2 = row2 - b2 * NTOK;
                        out2[(((long long)(b2 * NHEADS + hh)) * HD + e) * NTOK + n2] = ldsT[e * 136 + r + j];
                    }
                }
            }
        }
    } else {
#pragma unroll
        for (int tr = 0; tr < 4; ++tr) {
#pragma unroll
            for (int tc = 0; tc < 4; ++tc) {
                const int col = n0 + wn * 64 + tc * 16 + l15;
#pragma unroll
                for (int i = 0; i < 4; ++i) {
                    const int row = m0 + wm * 64 + tr * 16 + lq * 4 + i;
                    if (row >= M) continue;
                    const float v = acc[tr][tc][i];
                    if (MODE == 0) {
                        const int b = row / NTOK;
                        const int n = row - b * NTOK;
                        const int tq = col / CDIM;
                        const int rem = col - tq * CDIM;
                        const int h = rem >> 6;
                        const int e = rem & 63;
                        const long long gh = (long long)b * NHEADS + h;
                        if (tq == 0) out0[(gh * NTOK + n) * HD + e] = __float2bfloat16(v * QSCALE);  // Q
                        else         out1[(gh * NTOK + n) * HD + e] = __float2bfloat16(v);           // K
                    } else {
                        outf[(long long)row * CDIM + col] = v + biasf[col];
                    }
                }
            }
        }
    }
}

// ---------------------------------------------------------------------------
// Flash image attention v14 (256 thr = 4 waves) + fused text attention:
// grid (96, 9); qt < 8 -> image 128-row Q-tile (32 rows/wave as two 16-row
// halves rh), qt == 8 -> text path.
// v14 = v13 body with __launch_bounds__(256, 2): R8 proved the body fits
// in 84 VGPRs spill-free under min-waves=2; R9 proved min-waves=4 makes
// the allocator pin 64 VGPRs and spill 12 MB. Grid 864 = 3.4 blocks/CU
// (TLP binding limit), LDS 32 KB, so occupancy is unchanged by this edit.
// Fragment-sharing: one kf/vf LDS read feeds both rh halves -> per-output
// LDS read traffic halves vs v5 (LDS pipe ~85% busy is the bottleneck).
// ---------------------------------------------------------------------------
__global__ __launch_bounds__(256, 2) void flash_img(
    const __hip_bfloat16* __restrict__ Q,   // [96][1064][64] (pre-scaled)
    const __hip_bfloat16* __restrict__ Kt,  // [96][1064][64]
    const __hip_bfloat16* __restrict__ VT,  // [96][64][1064]
    __hip_bfloat16* __restrict__ AO)        // [8][1064][768]
{
    __shared__ __hip_bfloat16 smem[16384];   // 32 KB: 2 bufs of 8192 (K 4096 | V 4096)
    const int gh = blockIdx.x;
    const int qt = blockIdx.y;
    const int tid = threadIdx.x;
    const int w = tid >> 6, l = tid & 63, l15 = l & 15, lq = l >> 4;

    const __hip_bfloat16* Kg = Kt + (long long)gh * NTOK * HD;
    const __hip_bfloat16* Vg = VT + (long long)gh * HD * NTOK;

    if (qt == 8) {
        // ---------------- text attention path (40 q over 40 k) ----------------
        const int b = gh / NHEADS;
        const int h = gh - b * NHEADS;
        float* fs = (float*)smem;
        float* Qs = fs;                  // [40][65]... total 31200 B < 32 KB
        float* Ks = fs + 40 * 65;
        float* Vs = fs + 2 * 40 * 65;
        const __hip_bfloat16* Qg = Q + (long long)gh * NTOK * HD;
        for (int idx = tid; idx < 40 * 64; idx += 256) {
            const int n = idx >> 6;
            const int e = idx & 63;
            Qs[n * 65 + e] = __bfloat162float(Qg[n * HD + e]);
            Ks[n * 65 + e] = __bfloat162float(Kg[n * HD + e]);
            Vs[n * 65 + e] = __bfloat162float(Vg[(long long)e * NTOK + n]);
        }
        __syncthreads();
        for (int i = w; i < TT; i += 4) {
            float s = -1e30f;
            if (l < TT) {
                float a = 0.0f;
                for (int e = 0; e < 64; ++e) a += Qs[i * 65 + e] * Ks[l * 65 + e];
                s = a;                   // Q pre-scaled: already base-2 units
            }
            float m = s;
            for (int off = 32; off > 0; off >>= 1) m = fmaxf(m, __shfl_xor(m, off));
            float pr = (l < TT) ? exp2f(s - m) : 0.0f;
            float ssum = pr;
            for (int off = 32; off > 0; off >>= 1) ssum += __shfl_xor(ssum, off);
            pr /= ssum;
            float o = 0.0f;
            for (int j = 0; j < TT; ++j) o += __shfl(pr, j) * Vs[j * 65 + l];
            AO[((long long)b * NTOK + i) * CDIM + h * HD + l] = __float2bfloat16(o);
        }
        return;
    }

    // ---------------- image flash path (128-row Q tile, 32 rows/wave) --------
    const __hip_bfloat16* Qg = Q + ((long long)gh * NTOK + TT + qt * 128) * HD;

    bf16x8 qf[2][2];
#pragma unroll
    for (int rh = 0; rh < 2; ++rh)
#pragma unroll
        for (int kk = 0; kk < 2; ++kk)
            qf[rh][kk] = *(const bf16x8*)(Qg + (w * 32 + rh * 16 + l15) * HD + kk * 32 + lq * 8);

    f32x4 ot[2][4] = {};
    float lsum[2] = {0.0f, 0.0f};

    // stage tile t2 into buffer kb (4 global_load_lds per thread, 256 thr)
    auto stage = [&](int t2, __hip_bfloat16* kb) {
        const int np = t2 * 64;
#pragma unroll
        for (int half = 0; half < 2; ++half) {
            const int c = tid + half * 256;
            const int r0 = c >> 3;
            const int g0 = ((c & 7) - r0) & 7;
            int kr = np + r0; if (kr > NTOK - 1) kr = NTOK - 1;
            int vc = np + g0 * 8; if (vc > NTOK - 8) vc = NTOK - 8;
            load_lds16(Kg + (long long)kr * HD + g0 * 8, kb + c * 8);
            load_lds16(Vg + (long long)r0 * NTOK + vc, kb + 4096 + c * 8);
        }
    };

    stage(0, smem);

    const int segA = ((lq + l15) & 7) * 8;
    const int segB = ((4 + lq + l15) & 7) * 8;
    const int L0 = ((l & 16) ? 32 : 0) + l15;
    const int L1 = L0 + 16;
    const bool hi = (l & 32) != 0;

    for (int kt = 0; kt < 17; ++kt) {
        __syncthreads();

        if (kt < 16) stage(kt + 1, smem + ((kt + 1) & 1) * 8192);

        const __hip_bfloat16* kbuf = smem + (kt & 1) * 8192;
        const __hip_bfloat16* vbuf = kbuf + 4096;

        // ---- QK^T: one kf read feeds BOTH rh halves ----
        f32x4 st[2][4] = {};
#pragma unroll
        for (int kk = 0; kk < 2; ++kk) {
            const int seg = kk ? segB : segA;
            bf16x8 kf[4];
#pragma unroll
            for (int t = 0; t < 4; ++t)
                kf[t] = *(const bf16x8*)(kbuf + (t * 16 + l15) * 64 + seg);
#pragma unroll
            for (int t = 0; t < 4; ++t) {
                st[0][t] = __builtin_amdgcn_mfma_f32_16x16x32_bf16(kf[t], qf[0][kk], st[0][t], 0, 0, 0);
                st[1][t] = __builtin_amdgcn_mfma_f32_16x16x32_bf16(kf[t], qf[1][kk], st[1][t], 0, 0, 0);
            }
        }

        if (kt == 16) {
#pragma unroll
            for (int rh = 0; rh < 2; ++rh)
#pragma unroll
                for (int t = 0; t < 4; ++t) {
                    const int nb = 1024 + t * 16 + lq * 4;
#pragma unroll
                    for (int i = 0; i < 4; ++i)
                        if (nb + i >= NTOK) st[rh][t][i] = -1e30f;
                }
        }

        unsigned pk[2][4][2];
#pragma unroll
        for (int rh = 0; rh < 2; ++rh) {
            float rs = 0.0f;
#pragma unroll
            for (int t = 0; t < 4; ++t)
#pragma unroll
                for (int i = 0; i < 4; ++i) {
                    const float p = exp2f(st[rh][t][i]);
                    st[rh][t][i] = p;
                    rs += p;
                }
            lsum[rh] += rs;
#pragma unroll
            for (int t = 0; t < 4; ++t)
#pragma unroll
                for (int h = 0; h < 2; ++h) {
                    __hip_bfloat162 b2 = __float22bfloat162_rn(
                        make_float2(st[rh][t][2 * h], st[rh][t][2 * h + 1]));
                    pk[rh][t][h] = *(unsigned*)&b2;
                }
        }

        // ---- PV: one vf read feeds BOTH rh halves ----
#pragma unroll
        for (int kk = 0; kk < 2; ++kk) {
            const int seg = kk ? segB : segA;
            bf16x8 vf[4];
#pragma unroll
            for (int te = 0; te < 4; ++te)
                vf[te] = *(const bf16x8*)(vbuf + (te * 16 + l15) * 64 + seg);
#pragma unroll
            for (int rh = 0; rh < 2; ++rh) {
                const unsigned a0 = __shfl(pk[rh][2 * kk][0], L0), b0 = __shfl(pk[rh][2 * kk + 1][0], L0);
                const unsigned a1 = __shfl(pk[rh][2 * kk][1], L0), b1 = __shfl(pk[rh][2 * kk + 1][1], L0);
                const unsigned a2 = __shfl(pk[rh][2 * kk][0], L1), b2 = __shfl(pk[rh][2 * kk + 1][0], L1);
                const unsigned a3 = __shfl(pk[rh][2 * kk][1], L1), b3 = __shfl(pk[rh][2 * kk + 1][1], L1);
                union { unsigned u[4]; bf16x8 v; } pu;
                pu.u[0] = hi ? b0 : a0;
                pu.u[1] = hi ? b1 : a1;
                pu.u[2] = hi ? b2 : a2;
                pu.u[3] = hi ? b3 : a3;
#pragma unroll
                for (int te = 0; te < 4; ++te)
                    ot[rh][te] = __builtin_amdgcn_mfma_f32_16x16x32_bf16(vf[te], pu.v, ot[rh][te], 0, 0, 0);
            }
        }
    }

#pragma unroll
    for (int rh = 0; rh < 2; ++rh) {
        lsum[rh] += __shfl_xor(lsum[rh], 16);
        lsum[rh] += __shfl_xor(lsum[rh], 32);
    }
    const float inv0 = 1.0f / lsum[0];
    const float inv1 = 1.0f / lsum[1];

    __syncthreads();
    __hip_bfloat16* obuf = smem;                 // [128][72] = 18 KB
#pragma unroll
    for (int rh = 0; rh < 2; ++rh) {
        const float inv = rh ? inv1 : inv0;
#pragma unroll
        for (int te = 0; te < 4; ++te) {
            __hip_bfloat162 x0, x1;
            x0.x = __float2bfloat16(ot[rh][te][0] * inv);
            x0.y = __float2bfloat16(ot[rh][te][1] * inv);
            x1.x = __float2bfloat16(ot[rh][te][2] * inv);
            x1.y = __float2bfloat16(ot[rh][te][3] * inv);
            uint2 u;
            u.x = *(unsigned*)&x0;
            u.y = *(unsigned*)&x1;
            *(uint2*)(obuf + (w * 32 + rh * 16 + l15) * 72 + te * 16 + lq * 4) = u;
        }
    }
    __syncthreads();
    {
        const int b = gh / NHEADS, h = gh - b * NHEADS;
        const int r = tid >> 1, cc = (tid & 1) * 32;
        const int token = TT + qt * 128 + r;
        __hip_bfloat16* dst = AO + ((long long)b * NTOK + token) * CDIM + h * HD + cc;
        *(uint4*)dst        = *(const uint4*)(obuf + r * 72 + cc);
        *(uint4*)(dst + 8)  = *(const uint4*)(obuf + r * 72 + cc + 8);
        *(uint4*)(dst + 16) = *(const uint4*)(obuf + r * 72 + cc + 16);
        *(uint4*)(dst + 24) = *(const uint4*)(obuf + r * 72 + cc + 24);
    }
}

extern "C" void kernel_launch(void* const* d_in, const int* in_sizes, int n_in,
                              void* d_out, int out_size, void* d_ws, size_t ws_size,
                              hipStream_t stream)
{
    const float* x      = (const float*)d_in[0];
    const float* qkv_w  = (const float*)d_in[1];
    const float* proj_w = (const float*)d_in[2];
    const float* proj_b = (const float*)d_in[3];
    float* out = (float*)d_out;

    const long long QKV_ELEMS = (long long)8 * NHEADS * NTOK * HD;  // 6,537,216
    __hip_bfloat16* Q  = (__hip_bfloat16*)d_ws;
    __hip_bfloat16* Kt = Q + QKV_ELEMS;
    __hip_bfloat16* VT = Kt + QKV_ELEMS;
    __hip_bfloat16* AO = VT + QKV_ELEMS;        // [8][1064][768]; ALIASES xb (dead after QKV)
    __hip_bfloat16* xb = AO;
    __hip_bfloat16* wb = AO + QKV_ELEMS;        // qkv_w bf16 [2304][768]
    __hip_bfloat16* pb = wb + (long long)3 * CDIM * CDIM;  // proj_w bf16 [768][768]

    // 0. fused fp32 -> bf16 converts
    f2b3<<<4344, 256, 0, stream>>>(x, xb, qkv_w, wb, proj_w, pb);

    // 1. QKV GEMM: M=8512, N=2304, K=768 -> scatter Q (pre-scaled)/K/VT
    gemm128<0><<<dim3(18, 67), 256, 0, stream>>>(
        xb, CDIM, 8 * NTOK, wb, CDIM, CDIM,
        Q, Kt, VT, nullptr, nullptr);

    // 2+3. fused text + flash image attention (gh fastest -> XCD-local K/V)
    flash_img<<<dim3(96, 9), 256, 0, stream>>>(Q, Kt, VT, AO);

    // 4. proj GEMM + bias -> fp32 out
    gemm128<3><<<dim3(6, 67), 256, 0, stream>>>(
        AO, CDIM, 8 * NTOK, pb, CDIM, CDIM,
        nullptr, nullptr, nullptr, out, proj_b);
}

// Round 12
// 208.167 us; speedup vs baseline: 1.1145x; 1.0584x over previous
//
#include <hip/hip_runtime.h>
#include <hip/hip_bf16.h>

typedef __bf16 bf16x8 __attribute__((ext_vector_type(8)));
typedef float f32x4 __attribute__((ext_vector_type(4)));

#define NHEADS 12
#define TT 40
#define ST 1024
#define NTOK 1064
#define CDIM 768
#define HD 64
#define QSCALE 0.18033688f   // 0.125 * log2(e), folded into Q at QKV time

union U4 {
    uint4 u;
    __hip_bfloat16 h[8];
    bf16x8 v;
};

__device__ __forceinline__ void load_lds16(const __hip_bfloat16* g, __hip_bfloat16* s)
{
    __builtin_amdgcn_global_load_lds(
        (const __attribute__((address_space(1))) void*)g,
        (__attribute__((address_space(3))) void*)s, 16, 0, 0);
}

// Fused fp32 -> bf16 convert for x, qkv_w, proj_w (8 elems/thread).
__global__ __launch_bounds__(256) void f2b3(
    const float* __restrict__ x,  __hip_bfloat16* __restrict__ xo,
    const float* __restrict__ w,  __hip_bfloat16* __restrict__ wo,
    const float* __restrict__ p,  __hip_bfloat16* __restrict__ po)
{
    const float* in; __hip_bfloat16* out; int i;
    if (blockIdx.x < 3192)      { in = x; out = xo; i = blockIdx.x * 256 + threadIdx.x; if (i >= 817152) return; }
    else if (blockIdx.x < 4056) { in = w; out = wo; i = (blockIdx.x - 3192) * 256 + threadIdx.x; if (i >= 221184) return; }
    else                        { in = p; out = po; i = (blockIdx.x - 4056) * 256 + threadIdx.x; if (i >= 73728) return; }
    float4 a = ((const float4*)in)[2 * i];
    float4 b = ((const float4*)in)[2 * i + 1];
    U4 r;
    r.h[0] = __float2bfloat16(a.x); r.h[1] = __float2bfloat16(a.y);
    r.h[2] = __float2bfloat16(a.z); r.h[3] = __float2bfloat16(a.w);
    r.h[4] = __float2bfloat16(b.x); r.h[5] = __float2bfloat16(b.y);
    r.h[6] = __float2bfloat16(b.z); r.h[7] = __float2bfloat16(b.w);
    ((uint4*)out)[i] = r.u;
}

// ---------------------------------------------------------------------------
// 128x128x32 NT GEMM v10: DEPTH-2 async staging pipeline. 3 LDS buffers,
// raw s_barrier + counted s_waitcnt vmcnt(4) (never 0 in steady state).
// MODE 0: QKV scatter (Q pre-scaled; VT via LDS-transposed epilogue).
// MODE 3: proj+bias -> fp32. XCD-chunked bijective block swizzle.
// (verified win: QKV 73.5 -> ~60 us in R6)
// ---------------------------------------------------------------------------
template <int MODE>
__global__ __launch_bounds__(256) void gemm128(
    const __hip_bfloat16* __restrict__ A, int lda, int M,
    const __hip_bfloat16* __restrict__ B, int ldb,
    int K,
    __hip_bfloat16* __restrict__ out0,
    __hip_bfloat16* __restrict__ out1,
    __hip_bfloat16* __restrict__ out2,
    float* __restrict__ outf,
    const float* __restrict__ biasf)
{
    __shared__ __hip_bfloat16 lds[24576];   // 48 KB: buf b at b*8192: A 4096 | B 4096

    const int tid = threadIdx.x;

    // bijective XCD chunked swizzle (ERRATA #11-safe for any block count)
    const int nbx = gridDim.x, nwg = nbx * gridDim.y;
    const int linear = blockIdx.y * nbx + blockIdx.x;
    const int qc = nwg >> 3, rc = nwg & 7;
    const int xcd = linear & 7, idx = linear >> 3;
    const int swz = (xcd < rc ? xcd * (qc + 1) : rc * (qc + 1) + (xcd - rc) * qc) + idx;
    const int bx = swz % nbx, by = swz / nbx;

    const int m0 = by * 128;
    const int n0 = bx * 128;
    const int w = tid >> 6, l = tid & 63, l15 = l & 15, lq = l >> 4;
    const int wm = w >> 1, wn = w & 1;

    const __hip_bfloat16* srcA[2];
    const __hip_bfloat16* srcB[2];
    int c8[2];
#pragma unroll
    for (int rd = 0; rd < 2; ++rd) {
        const int c = tid + rd * 256;
        const int r = c >> 2, cs = c & 3;
        const int gs = (cs - (r >> 1)) & 3;
        int ra = m0 + r; if (ra > M - 1) ra = M - 1;
        srcA[rd] = A + (long long)ra * lda + gs * 8;
        srcB[rd] = B + (long long)(n0 + r) * ldb + gs * 8;
        c8[rd] = c * 8;
    }

    int offA[4], offB[4];
#pragma unroll
    for (int t = 0; t < 4; ++t) {
        { const int r = wm * 64 + t * 16 + l15;
          offA[t] = r * 32 + ((lq + (r >> 1)) & 3) * 8; }
        { const int r = wn * 64 + t * 16 + l15;
          offB[t] = r * 32 + ((lq + (r >> 1)) & 3) * 8; }
    }

    f32x4 acc[4][4] = {};

    const int ksteps = K / 32;   // 24 for both dispatches (>= 2)
    // prologue: stage tile 0 -> buf 0, tile 1 -> buf 1
#pragma unroll
    for (int rd = 0; rd < 2; ++rd) {
        load_lds16(srcA[rd], lds + c8[rd]);
        load_lds16(srcB[rd], lds + 4096 + c8[rd]);
    }
#pragma unroll
    for (int rd = 0; rd < 2; ++rd) {
        load_lds16(srcA[rd] + 32, lds + 8192 + c8[rd]);
        load_lds16(srcB[rd] + 32, lds + 8192 + 4096 + c8[rd]);
    }

    int bcur = 0;
    for (int ks = 0; ks < ksteps; ++ks) {
        // wait for tile ks only (tile ks+1 stays in flight), then barrier
        if (ks + 1 < ksteps) { asm volatile("s_waitcnt vmcnt(4)" ::: "memory"); }
        else                 { asm volatile("s_waitcnt vmcnt(0)" ::: "memory"); }
        __builtin_amdgcn_s_barrier();
        __builtin_amdgcn_sched_barrier(0);   // pin: no ds_read hoisted above

        if (ks + 2 < ksteps) {   // stage tile ks+2 into the freed buffer
            const int bnxt = (bcur + 2 >= 3) ? bcur - 1 : bcur + 2;
            const int o = bnxt * 8192;
            const int koff = (ks + 2) * 32;
#pragma unroll
            for (int rd = 0; rd < 2; ++rd) {
                load_lds16(srcA[rd] + koff, lds + o + c8[rd]);
                load_lds16(srcB[rd] + koff, lds + o + 4096 + c8[rd]);
            }
        }

        const __hip_bfloat16* bufA = lds + bcur * 8192;
        const __hip_bfloat16* bufB = bufA + 4096;

        bf16x8 af[4], bfr[4];
#pragma unroll
        for (int t = 0; t < 4; ++t) af[t] = *(const bf16x8*)(bufA + offA[t]);
#pragma unroll
        for (int t = 0; t < 4; ++t) bfr[t] = *(const bf16x8*)(bufB + offB[t]);
#pragma unroll
        for (int tr = 0; tr < 4; ++tr)
#pragma unroll
            for (int tc = 0; tc < 4; ++tc)
                acc[tr][tc] = __builtin_amdgcn_mfma_f32_16x16x32_bf16(af[tr], bfr[tc], acc[tr][tc], 0, 0, 0);

        bcur = (bcur == 2) ? 0 : bcur + 1;
    }

    if (MODE == 0 && n0 >= 1536) {
        __hip_bfloat16* ldsT = lds;                  // [64 cols][136 rows]
#pragma unroll
        for (int hf = 0; hf < 2; ++hf) {
            __syncthreads();
            if (wn == hf) {
#pragma unroll
                for (int tr = 0; tr < 4; ++tr)
#pragma unroll
                    for (int tc = 0; tc < 4; ++tc) {
                        const int cl = tc * 16 + l15;
                        const int r = wm * 64 + tr * 16 + lq * 4;
                        U4 pk4;
                        pk4.h[0] = __float2bfloat16(acc[tr][tc][0]);
                        pk4.h[1] = __float2bfloat16(acc[tr][tc][1]);
                        pk4.h[2] = __float2bfloat16(acc[tr][tc][2]);
                        pk4.h[3] = __float2bfloat16(acc[tr][tc][3]);
                        *(uint2*)(ldsT + cl * 136 + r) = make_uint2(pk4.u.x, pk4.u.y);
                    }
            }
            __syncthreads();
            const int e = tid >> 2, rseg = (tid & 3) * 32;
            const int hh = (n0 + hf * 64 - 1536) >> 6;
#pragma unroll
            for (int j4 = 0; j4 < 4; ++j4) {
                const int r = rseg + j4 * 8;
                const int row = m0 + r;
                if (row >= 8 * NTOK) continue;
                const int b = row / NTOK;
                const int n = row - b * NTOK;
                __hip_bfloat16* dst = out2 + (((long long)(b * NHEADS + hh)) * HD + e) * NTOK + n;
                if (n + 8 <= NTOK) {
                    *(uint4*)dst = *(const uint4*)(ldsT + e * 136 + r);
                } else {
                    for (int j = 0; j < 8; ++j) {
                        const int row2 = row + j;
                        const int b2 = row2 / NTOK;
                        const int n2 = row2 - b2 * NTOK;
                        out2[(((long long)(b2 * NHEADS + hh)) * HD + e) * NTOK + n2] = ldsT[e * 136 + r + j];
                    }
                }
            }
        }
    } else {
#pragma unroll
        for (int tr = 0; tr < 4; ++tr) {
#pragma unroll
            for (int tc = 0; tc < 4; ++tc) {
                const int col = n0 + wn * 64 + tc * 16 + l15;
#pragma unroll
                for (int i = 0; i < 4; ++i) {
                    const int row = m0 + wm * 64 + tr * 16 + lq * 4 + i;
                    if (row >= M) continue;
                    const float v = acc[tr][tc][i];
                    if (MODE == 0) {
                        const int b = row / NTOK;
                        const int n = row - b * NTOK;
                        const int tq = col / CDIM;
                        const int rem = col - tq * CDIM;
                        const int h = rem >> 6;
                        const int e = rem & 63;
                        const long long gh = (long long)b * NHEADS + h;
                        if (tq == 0) out0[(gh * NTOK + n) * HD + e] = __float2bfloat16(v * QSCALE);  // Q
                        else         out1[(gh * NTOK + n) * HD + e] = __float2bfloat16(v);           // K
                    } else {
                        outf[(long long)row * CDIM + col] = v + biasf[col];
                    }
                }
            }
        }
    }
}

// ---------------------------------------------------------------------------
// Flash image attention v15 (512 thr = 8 waves) + fused text attention:
// grid (96, 9); qt < 8 -> image 128-row Q-tile, qt == 8 -> text path.
// v15 = v5 with ZERO-SHUFFLE softmax->PV handoff: K-tile rows are staged
// PRE-PERMUTED by the bit-permutation kappa(r) (token bits [r4,r3,r2,r5,
// r1,r0]) so QK^T's natural C-layout ownership (lane lq owns rows
// 16t+4lq+i) coincides with PV's B-operand needs (lane lq needs slots
// 8lq+2d+p). Token order within a tile is arbitrary (softmax sum and PV
// are order-invariant; V stays natural order = B slot order). Deletes all
// 16 ds_bpermute + 8 cndmask per wave-kt (~38% of the saturated LDS pipe,
// which R10 pinned at ~97% busy). Structure/TLP/VGPR otherwise v5.
// ---------------------------------------------------------------------------
__global__ __launch_bounds__(512) void flash_img(
    const __hip_bfloat16* __restrict__ Q,   // [96][1064][64] (pre-scaled)
    const __hip_bfloat16* __restrict__ Kt,  // [96][1064][64]
    const __hip_bfloat16* __restrict__ VT,  // [96][64][1064]
    __hip_bfloat16* __restrict__ AO)        // [8][1064][768]
{
    __shared__ __hip_bfloat16 smem[16384];   // 32 KB
    const int gh = blockIdx.x;
    const int qt = blockIdx.y;
    const int tid = threadIdx.x;
    const int w = tid >> 6, l = tid & 63, l15 = l & 15, lq = l >> 4;

    const __hip_bfloat16* Kg = Kt + (long long)gh * NTOK * HD;
    const __hip_bfloat16* Vg = VT + (long long)gh * HD * NTOK;

    if (qt == 8) {
        // ---------------- text attention path (40 q over 40 k) ----------------
        const int b = gh / NHEADS;
        const int h = gh - b * NHEADS;
        float* fs = (float*)smem;
        float* Qs = fs;                  // [40][65]
        float* Ks = fs + 40 * 65;
        float* Vs = fs + 2 * 40 * 65;    // total 31200 B < 32 KB
        const __hip_bfloat16* Qg = Q + (long long)gh * NTOK * HD;
        for (int idx = tid; idx < 40 * 64; idx += 512) {
            const int n = idx >> 6;
            const int e = idx & 63;
            Qs[n * 65 + e] = __bfloat162float(Qg[n * HD + e]);
            Ks[n * 65 + e] = __bfloat162float(Kg[n * HD + e]);
            Vs[n * 65 + e] = __bfloat162float(Vg[(long long)e * NTOK + n]);
        }
        __syncthreads();
        for (int i = w; i < TT; i += 8) {
            float s = -1e30f;
            if (l < TT) {
                float a = 0.0f;
                for (int e = 0; e < 64; ++e) a += Qs[i * 65 + e] * Ks[l * 65 + e];
                s = a;                   // Q pre-scaled: already base-2 units
            }
            float m = s;
            for (int off = 32; off > 0; off >>= 1) m = fmaxf(m, __shfl_xor(m, off));
            float pr = (l < TT) ? exp2f(s - m) : 0.0f;
            float ssum = pr;
            for (int off = 32; off > 0; off >>= 1) ssum += __shfl_xor(ssum, off);
            pr /= ssum;
            float o = 0.0f;
            for (int j = 0; j < TT; ++j) o += __shfl(pr, j) * Vs[j * 65 + l];
            AO[((long long)b * NTOK + i) * CDIM + h * HD + l] = __float2bfloat16(o);
        }
        return;
    }

    // ---------------- image flash path ----------------
    const __hip_bfloat16* Qg = Q + ((long long)gh * NTOK + TT + qt * 128) * HD;

    const int r0 = tid >> 3;
    const int g0 = ((tid & 7) - r0) & 7;
    // kappa: K-row r0 holds token kappa(r0); token bits = [r4,r3,r2,r5,r1,r0]
    const int rperm = ((r0 & 0x10) << 1) | ((r0 & 0x0C) << 1) | ((r0 & 0x20) >> 3) | (r0 & 3);

    bf16x8 qf[2];
#pragma unroll
    for (int kk = 0; kk < 2; ++kk)
        qf[kk] = *(const bf16x8*)(Qg + (w * 16 + l15) * HD + kk * 32 + lq * 8);

    f32x4 ot[4] = {};
    float lsum = 0.0f;

    {
        int kr = rperm;                       // tile 0: tokens 0..63, no clamp needed
        load_lds16(Kg + (long long)kr * HD + g0 * 8, smem + tid * 8);
        load_lds16(Vg + (long long)r0 * NTOK + g0 * 8, smem + 4096 + tid * 8);
    }

    const int segA = ((lq + l15) & 7) * 8;
    const int segB = ((4 + lq + l15) & 7) * 8;

    for (int kt = 0; kt < 17; ++kt) {
        __syncthreads();

        if (kt < 16) {
            const int np = (kt + 1) * 64;
            __hip_bfloat16* kb = smem + ((kt + 1) & 1) * 8192;
            int kr = np + rperm; if (kr > NTOK - 1) kr = NTOK - 1;
            int vc = np + g0 * 8; if (vc > NTOK - 8) vc = NTOK - 8;
            load_lds16(Kg + (long long)kr * HD + g0 * 8, kb + tid * 8);
            load_lds16(Vg + (long long)r0 * NTOK + vc, kb + 4096 + tid * 8);
        }

        const __hip_bfloat16* kbuf = smem + (kt & 1) * 8192;
        const __hip_bfloat16* vbuf = kbuf + 4096;

        f32x4 st[4] = {};
#pragma unroll
        for (int kk = 0; kk < 2; ++kk) {
            const int seg = kk ? segB : segA;
            bf16x8 kf[4];
#pragma unroll
            for (int t = 0; t < 4; ++t)
                kf[t] = *(const bf16x8*)(kbuf + (t * 16 + l15) * 64 + seg);
#pragma unroll
            for (int t = 0; t < 4; ++t)
                st[t] = __builtin_amdgcn_mfma_f32_16x16x32_bf16(kf[t], qf[kk], st[t], 0, 0, 0);
        }

        if (kt == 16) {
            // physical row r = 16t+4lq+i holds token kappa(r); mask tokens >= 40
#pragma unroll
            for (int t = 0; t < 4; ++t)
#pragma unroll
                for (int i = 0; i < 4; ++i) {
                    const int tok = 32 * (t & 1) + 4 * (t >> 1) + 2 * (i >> 1) + (i & 1) + 8 * lq;
                    if (tok >= 40) st[t][i] = -1e30f;
                }
        }

        float rs = 0.0f;
#pragma unroll
        for (int t = 0; t < 4; ++t)
#pragma unroll
            for (int i = 0; i < 4; ++i) {
                const float p = exp2f(st[t][i]);
                st[t][i] = p;
                rs += p;
            }
        lsum += rs;

        unsigned pk[4][2];
#pragma unroll
        for (int t = 0; t < 4; ++t)
#pragma unroll
            for (int h = 0; h < 2; ++h) {
                __hip_bfloat162 b2 = __float22bfloat162_rn(
                    make_float2(st[t][2 * h], st[t][2 * h + 1]));
                pk[t][h] = *(unsigned*)&b2;
            }

        // Zero-shuffle PV: kappa-permuted K rows make P lane-local for the
        // B-operand. pu(kk) = {pk[kk][0], pk[kk][1], pk[2+kk][0], pk[2+kk][1]}.
#pragma unroll
        for (int kk = 0; kk < 2; ++kk) {
            const int seg = kk ? segB : segA;
            bf16x8 vf[4];
#pragma unroll
            for (int te = 0; te < 4; ++te)
                vf[te] = *(const bf16x8*)(vbuf + (te * 16 + l15) * 64 + seg);
            union { unsigned u[4]; bf16x8 v; } pu;
            pu.u[0] = pk[kk][0];
            pu.u[1] = pk[kk][1];
            pu.u[2] = pk[2 + kk][0];
            pu.u[3] = pk[2 + kk][1];
#pragma unroll
            for (int te = 0; te < 4; ++te)
                ot[te] = __builtin_amdgcn_mfma_f32_16x16x32_bf16(vf[te], pu.v, ot[te], 0, 0, 0);
        }
    }

    lsum += __shfl_xor(lsum, 16);
    lsum += __shfl_xor(lsum, 32);

    __syncthreads();
    __hip_bfloat16* obuf = smem;                 // [128][72]
    const float inv = 1.0f / lsum;
#pragma unroll
    for (int te = 0; te < 4; ++te) {
        __hip_bfloat162 x0, x1;
        x0.x = __float2bfloat16(ot[te][0] * inv);
        x0.y = __float2bfloat16(ot[te][1] * inv);
        x1.x = __float2bfloat16(ot[te][2] * inv);
        x1.y = __float2bfloat16(ot[te][3] * inv);
        uint2 u;
        u.x = *(unsigned*)&x0;
        u.y = *(unsigned*)&x1;
        *(uint2*)(obuf + (w * 16 + l15) * 72 + te * 16 + lq * 4) = u;
    }
    __syncthreads();
    {
        const int b = gh / NHEADS, h = gh - b * NHEADS;
        const int r = tid >> 2, cc = (tid & 3) * 16;
        const int token = TT + qt * 128 + r;
        __hip_bfloat16* dst = AO + ((long long)b * NTOK + token) * CDIM + h * HD + cc;
        *(uint4*)dst       = *(const uint4*)(obuf + r * 72 + cc);
        *(uint4*)(dst + 8) = *(const uint4*)(obuf + r * 72 + cc + 8);
    }
}

extern "C" void kernel_launch(void* const* d_in, const int* in_sizes, int n_in,
                              void* d_out, int out_size, void* d_ws, size_t ws_size,
                              hipStream_t stream)
{
    const float* x      = (const float*)d_in[0];
    const float* qkv_w  = (const float*)d_in[1];
    const float* proj_w = (const float*)d_in[2];
    const float* proj_b = (const float*)d_in[3];
    float* out = (float*)d_out;

    const long long QKV_ELEMS = (long long)8 * NHEADS * NTOK * HD;  // 6,537,216
    __hip_bfloat16* Q  = (__hip_bfloat16*)d_ws;
    __hip_bfloat16* Kt = Q + QKV_ELEMS;
    __hip_bfloat16* VT = Kt + QKV_ELEMS;
    __hip_bfloat16* AO = VT + QKV_ELEMS;        // [8][1064][768]; ALIASES xb (dead after QKV)
    __hip_bfloat16* xb = AO;
    __hip_bfloat16* wb = AO + QKV_ELEMS;        // qkv_w bf16 [2304][768]
    __hip_bfloat16* pb = wb + (long long)3 * CDIM * CDIM;  // proj_w bf16 [768][768]

    // 0. fused fp32 -> bf16 converts
    f2b3<<<4344, 256, 0, stream>>>(x, xb, qkv_w, wb, proj_w, pb);

    // 1. QKV GEMM: M=8512, N=2304, K=768 -> scatter Q (pre-scaled)/K/VT
    gemm128<0><<<dim3(18, 67), 256, 0, stream>>>(
        xb, CDIM, 8 * NTOK, wb, CDIM, CDIM,
        Q, Kt, VT, nullptr, nullptr);

    // 2+3. fused text + flash image attention (gh fastest -> XCD-local K/V)
    flash_img<<<dim3(96, 9), 512, 0, stream>>>(Q, Kt, VT, AO);

    // 4. proj GEMM + bias -> fp32 out
    gemm128<3><<<dim3(6, 67), 256, 0, stream>>>(
        AO, CDIM, 8 * NTOK, pb, CDIM, CDIM,
        nullptr, nullptr, nullptr, out, proj_b);
}